// Round 9
// baseline (111.904 us; speedup 1.0000x reference)
//
#include <hip/hip_runtime.h>
#include <hip/hip_fp16.h>

// Ultimus: out = x + softmax((x@Kw+Kb)@(x@Qw+Qb)^T / sqrt(8)) @ (x@Vw+Vb) @ Zw + Zb
// N=8192, D_IN=48, D_ATTN=8, fp32 in/out.
//
// R20 = R19 (MFMA attn, verified correct: absmax 0.03125) + stall removal.
// R19 analysis: attn ~31us = ~10us exp2 floor (1M wave-instr v_exp_f32 at
// ~24cy -- fitted from R18's VALUBusy 67%x41.8 = 28us busy vs 16.4us of fma
// at 2cy) + ~6us VALU + ~15us STALLS. Stall sources in R19's tile loop:
// divergent (if h==0) Q-frag load + 4 dependent V loads inside a runtime
// 8-iteration loop (no compiler pipelining), prologue amortized over only
// 8 tiles. R20: (1) manual software pipeline -- prefetch tile t+1's Q/V
// into named regs while computing tile t; (2) de-diverged Q load: all lanes
// load, v_cndmask selects the bias constant for upper lanes; (3) V address
// base hoisted (clamped row min(hl,8); lanes 9-31 read ones-row, values
// land in unused C rows 9-31). Math identical to R19.
//
// MFMA structure (verified R19): v_mfma_f32_32x32x16_f16, D=8 padded K=16.
//  - scores: S^T = mfma(A=Q', B=K'); bias folded in pad slots (K' k8 =
//    sinit_r, Q' k8 = 1.0); pre-scaled by log2e/sqrt8 -> exp2 direct.
//  - PV: A = V'^T j-permuted to match C-layout reg order so P^T B-frags
//    are 8 cvt_pkrtz of consecutive C regs (zero cross-lane). Ones-row
//    c=8 of V'^T = free softmax denominator. f32 accumulation over tiles.
//
// ws layout (dwords/floats):
//   [0, 32768)        Xksf16[8192] 8 f16/row (k * log2e/sqrt(8)), uint4/row
//   [32768, 65536)    Qf16[8192]   8 f16/row (raw q), uint4/row
//   [65536, 102400)   Vt[9][8192]  f16, row-major; row 8 = 1.0 (denominator)
//   [102400, 110592)  kn2[8192]    f32 ||k_scaled||^2
//   [110592, 110848)  bmax[256]    per-proj-block max ||q||^2
//   [110848, ...)     part[nch][8192][9] f32 partials: acc[0:8], l at [8]

#define XKS_OFF  0
#define Q4_OFF   32768
#define VT_OFF   65536
#define KN2_OFF  102400
#define BMAX_OFF 110592
#define PART_OFF 110848

typedef _Float16 half8 __attribute__((ext_vector_type(8)));
typedef float f32x16 __attribute__((ext_vector_type(16)));
union U8 { unsigned u[4]; half8 h; };

static __device__ __forceinline__ unsigned pku(float a, float b) {
    auto t = __builtin_amdgcn_cvt_pkrtz(a, b);
    union { decltype(t) x; unsigned u; } c; c.x = t; return c.u;
}

__global__ __launch_bounds__(256) void proj_kernel(
    const float* __restrict__ x,
    const float* __restrict__ Kw, const float* __restrict__ Kb,
    const float* __restrict__ Qw, const float* __restrict__ Qb,
    const float* __restrict__ Vw, const float* __restrict__ Vb,
    unsigned* __restrict__ Xksf16, unsigned* __restrict__ Q4,
    unsigned* __restrict__ Vt, float* __restrict__ kn2,
    float* __restrict__ bmax)
{
    __shared__ float xs[32 * 49];     // +1 pad
    __shared__ float wAll[3 * 388];   // stride 388 (mod 32 = 4) spreads 3 mats
    __shared__ float bs[24];
    __shared__ float outv[32][25];    // 24 cols + pad
    const int tid = threadIdx.x;
    const int r0 = blockIdx.x * 32;

    for (int i = tid; i < 1536; i += 256) {
        int r = i / 48, c = i - r * 48;
        xs[r * 49 + c] = x[r0 * 48 + i];
    }
    for (int i = tid; i < 384; i += 256) {
        wAll[i]       = Kw[i];
        wAll[388 + i] = Qw[i];
        wAll[776 + i] = Vw[i];
    }
    if (tid < 8)       bs[tid] = Kb[tid];
    else if (tid < 16) bs[tid] = Qb[tid - 8];
    else if (tid < 24) bs[tid] = Vb[tid - 16];
    __syncthreads();

    const int rl = tid >> 3;
    const int g  = tid & 7;
    const int c0 = 3 * g;
    const float* xr = &xs[rl * 49];
    const float* w0 = &wAll[((c0 + 0) >> 3) * 388 + ((c0 + 0) & 7)];
    const float* w1 = &wAll[((c0 + 1) >> 3) * 388 + ((c0 + 1) & 7)];
    const float* w2 = &wAll[((c0 + 2) >> 3) * 388 + ((c0 + 2) & 7)];
    float a0 = bs[c0], a1 = bs[c0 + 1], a2 = bs[c0 + 2];
    #pragma unroll
    for (int k = 0; k < 48; k++) {
        const float xv = xr[k];
        a0 = fmaf(xv, w0[k * 8], a0);
        a1 = fmaf(xv, w1[k * 8], a1);
        a2 = fmaf(xv, w2[k * 8], a2);
    }
    outv[rl][c0] = a0; outv[rl][c0 + 1] = a1; outv[rl][c0 + 2] = a2;
    __syncthreads();

    const float kscale = 0.51008732149f;  // (1/sqrt(8)) * log2(e)
    if (tid < 32) {                       // K rows, f16 packed, pre-scaled
        uint4 o;
        o.x = pku(outv[tid][0] * kscale, outv[tid][1] * kscale);
        o.y = pku(outv[tid][2] * kscale, outv[tid][3] * kscale);
        o.z = pku(outv[tid][4] * kscale, outv[tid][5] * kscale);
        o.w = pku(outv[tid][6] * kscale, outv[tid][7] * kscale);
        ((uint4*)Xksf16)[r0 + tid] = o;
    } else if (tid < 64) {                // Q rows, f16 packed, raw
        const int r = tid - 32;
        uint4 o;
        o.x = pku(outv[r][8],  outv[r][9]);
        o.y = pku(outv[r][10], outv[r][11]);
        o.z = pku(outv[r][12], outv[r][13]);
        o.w = pku(outv[r][14], outv[r][15]);
        ((uint4*)Q4)[r0 + r] = o;
    } else if (tid < 192) {               // Vt[c][j] f16 pairs
        const int i = tid - 64;
        const int c = i >> 4, t = i & 15;
        Vt[c * 4096 + blockIdx.x * 16 + t] =
            pku(outv[2 * t][16 + c], outv[2 * t + 1][16 + c]);
    } else if (tid < 224) {               // block-max ||q||^2 (fp32)
        const int r = tid - 192;
        float n2 = 0.f;
        #pragma unroll
        for (int c = 0; c < 8; c++) n2 = fmaf(outv[r][8 + c], outv[r][8 + c], n2);
        #pragma unroll
        for (int off = 16; off > 0; off >>= 1)
            n2 = fmaxf(n2, __shfl_xor(n2, off, 64));
        if (r == 0) bmax[blockIdx.x] = n2;
    } else {                              // kn2 = ||k_scaled||^2
        const int r = tid - 224;
        float s = 0.f;
        #pragma unroll
        for (int c = 0; c < 8; c++) { const float v = outv[r][c]; s = fmaf(v, v, s); }
        kn2[r0 + r] = s * (kscale * kscale);
    }
    if (tid < 16)                          // ones row c=8 of Vt (denominator)
        Vt[8 * 4096 + blockIdx.x * 16 + tid] = 0x3C003C00u;
}

// wave = (rg, ch): 32 rows x (8192/nch) j, ntiles 32-j tiles. No LDS/barriers.
// Per tile: 1 score MFMA (bias in pad slot) -> 16 exp2 -> 8 cvt_pk -> 2 PV
// MFMA (f32 accum). Tile t+1's Q/V prefetched into named regs during tile t.
__global__ __launch_bounds__(256) void attn_kernel(
    const uint4* __restrict__ Xks4, const uint4* __restrict__ Q4,
    const unsigned* __restrict__ Vt, const float* __restrict__ kn2,
    const float* __restrict__ bmax, float* __restrict__ part, int ntiles)
{
    const int tid  = threadIdx.x;
    const int lane = tid & 63;
    const int wv   = tid >> 6;
    const int wid  = blockIdx.x * 4 + wv;
    const int rg = wid & 255, ch = wid >> 8;
    const int h = lane >> 5, hl = lane & 31;
    const int rbase = rg * 32;
    const int j0base = ch * (ntiles * 32);

    // qmax2 = max over 256 per-proj-block maxima
    float m = fmaxf(fmaxf(bmax[lane], bmax[64 + lane]),
                    fmaxf(bmax[128 + lane], bmax[192 + lane]));
    #pragma unroll
    for (int off = 32; off > 0; off >>= 1)
        m = fmaxf(m, __shfl_xor(m, off, 64));
    const float qmax2 = m;

    // B-frag = K': lanes<32 hold k0..7 of row rbase+hl; lanes>=32 hold
    // (sinit, 0,...) in k8..15 (bias slot).
    U8 Bk;
    if (h == 0) {
        const uint4 kv = Xks4[rbase + hl];
        Bk.u[0] = kv.x; Bk.u[1] = kv.y; Bk.u[2] = kv.z; Bk.u[3] = kv.w;
    } else {
        const float sinit = -sqrtf(kn2[rbase + hl] * qmax2);
        Bk.u[0] = pku(sinit, 0.f); Bk.u[1] = 0u; Bk.u[2] = 0u; Bk.u[3] = 0u;
    }

    const f32x16 zc = {0.f,0.f,0.f,0.f,0.f,0.f,0.f,0.f,
                       0.f,0.f,0.f,0.f,0.f,0.f,0.f,0.f};
    f32x16 acc = {0.f,0.f,0.f,0.f,0.f,0.f,0.f,0.f,
                  0.f,0.f,0.f,0.f,0.f,0.f,0.f,0.f};

    // Hoisted V base (uint2 units). Lanes hl>8 clamp to ones-row 8: their
    // values land in C rows 9-31, which are never read.
    const int cva = hl < 9 ? hl : 8;
    const uint2* V2 = (const uint2*)Vt;
    const int u2base = cva * 2048 + h;       // (cva*8192 + 4h) / 4

    // ---- prefetch tile 0 ----
    int j0 = j0base;
    uint4 qv_n  = Q4[j0 + hl];
    uint2 va0_n = V2[u2base + (j0 >> 2) + 0];
    uint2 va1_n = V2[u2base + (j0 >> 2) + 2];
    uint2 va2_n = V2[u2base + (j0 >> 2) + 4];
    uint2 va3_n = V2[u2base + (j0 >> 2) + 6];

    for (int t = 0; t < ntiles; ++t) {
        const uint4 qv  = qv_n;
        const uint2 va0 = va0_n, va1 = va1_n, va2 = va2_n, va3 = va3_n;
        if (t + 1 < ntiles) {               // issue next tile's loads NOW
            const int j1 = j0 + 32;
            qv_n  = Q4[j1 + hl];
            va0_n = V2[u2base + (j1 >> 2) + 0];
            va1_n = V2[u2base + (j1 >> 2) + 2];
            va2_n = V2[u2base + (j1 >> 2) + 4];
            va3_n = V2[u2base + (j1 >> 2) + 6];
        }

        // A-frag = Q' via cndmask (no divergence): lanes>=32 get 1.0 in k8.
        U8 Aq;
        Aq.u[0] = h ? 0x00003C00u : qv.x;
        Aq.u[1] = h ? 0u : qv.y;
        Aq.u[2] = h ? 0u : qv.z;
        Aq.u[3] = h ? 0u : qv.w;
        // S^T tile: lane holds col r=rbase+hl; regs = 16 j's
        const f32x16 s = __builtin_amdgcn_mfma_f32_32x32x16_f16(Aq.h, Bk.h, zc, 0, 0, 0);

        const unsigned pk01 = pku(__builtin_amdgcn_exp2f(s[0]),  __builtin_amdgcn_exp2f(s[1]));
        const unsigned pk23 = pku(__builtin_amdgcn_exp2f(s[2]),  __builtin_amdgcn_exp2f(s[3]));
        const unsigned pk45 = pku(__builtin_amdgcn_exp2f(s[4]),  __builtin_amdgcn_exp2f(s[5]));
        const unsigned pk67 = pku(__builtin_amdgcn_exp2f(s[6]),  __builtin_amdgcn_exp2f(s[7]));
        const unsigned pk89 = pku(__builtin_amdgcn_exp2f(s[8]),  __builtin_amdgcn_exp2f(s[9]));
        const unsigned pkAB = pku(__builtin_amdgcn_exp2f(s[10]), __builtin_amdgcn_exp2f(s[11]));
        const unsigned pkCD = pku(__builtin_amdgcn_exp2f(s[12]), __builtin_amdgcn_exp2f(s[13]));
        const unsigned pkEF = pku(__builtin_amdgcn_exp2f(s[14]), __builtin_amdgcn_exp2f(s[15]));

        // V'^T A-frags (j-permuted to C-layout reg order), P^T B-frags.
        U8 A2a; A2a.u[0] = va0.x; A2a.u[1] = va0.y; A2a.u[2] = va1.x; A2a.u[3] = va1.y;
        U8 B2a; B2a.u[0] = pk01;  B2a.u[1] = pk23;  B2a.u[2] = pk45;  B2a.u[3] = pk67;
        acc = __builtin_amdgcn_mfma_f32_32x32x16_f16(A2a.h, B2a.h, acc, 0, 0, 0);
        U8 A2b; A2b.u[0] = va2.x; A2b.u[1] = va2.y; A2b.u[2] = va3.x; A2b.u[3] = va3.y;
        U8 B2b; B2b.u[0] = pk89;  B2b.u[1] = pkAB;  B2b.u[2] = pkCD;  B2b.u[3] = pkEF;
        acc = __builtin_amdgcn_mfma_f32_32x32x16_f16(A2b.h, B2b.h, acc, 0, 0, 0);

        j0 += 32;
    }

    // acc reg R -> out[c=(R&3)+8*(R>>2)+4h][r=rbase+hl]; valid c<=8.
    float* pr = part + ((size_t)ch * 8192 + rbase + hl) * 9;
    if (h == 0) {
        pr[0] = acc[0]; pr[1] = acc[1]; pr[2] = acc[2]; pr[3] = acc[3];
        pr[8] = acc[4];                  // c=8 = ones row = denominator l
    } else {
        pr[4] = acc[0]; pr[5] = acc[1]; pr[6] = acc[2]; pr[7] = acc[3];
    }
}

// 256 blocks x 32 rows; reduction parallelized over all 256 threads
// (thread = (row, col)), so nch=32 partial sets stay cheap.
__global__ __launch_bounds__(256) void finish_kernel(
    const float* __restrict__ x,
    const float* __restrict__ Zw, const float* __restrict__ Zb,
    const float* __restrict__ part, float* __restrict__ out, int nch)
{
    __shared__ float Zs[32 * 9];
    __shared__ float Zl[32];
    __shared__ float zw_s[384];
    __shared__ float zb_s[48];
    const int tid = threadIdx.x;
    const int r0 = blockIdx.x * 32;

    for (int i = tid; i < 384; i += 256) zw_s[i] = Zw[i];
    if (tid < 48) zb_s[tid] = Zb[tid];

    // phase 1: thread = (row r = tid>>3, col c = tid&7); c==0 also sums l
    {
        const int r = tid >> 3, c = tid & 7;
        float a = 0.f, l = 0.f;
        #pragma unroll 8
        for (int ch = 0; ch < nch; ch++) {
            const float* p = part + ((size_t)ch * 8192 + r0 + r) * 9;
            a += p[c];
            if (c == 0) l += p[8];
        }
        if (c == 0) Zl[r] = l;
        __syncthreads();
        Zs[r * 9 + c] = a * (1.0f / Zl[r]);
    }
    __syncthreads();

    for (int e = tid; e < 32 * 48; e += 256) {
        const int r = e / 48, c = e - r * 48;
        float o = x[r0 * 48 + e] + zb_s[c];
        #pragma unroll
        for (int k = 0; k < 8; k++) o = fmaf(Zs[r * 9 + k], zw_s[k * 48 + c], o);
        out[r0 * 48 + e] = o;
    }
}

extern "C" void kernel_launch(void* const* d_in, const int* in_sizes, int n_in,
                              void* d_out, int out_size, void* d_ws, size_t ws_size,
                              hipStream_t stream) {
    const float* x  = (const float*)d_in[0];
    const float* Kw = (const float*)d_in[1];
    const float* Kb = (const float*)d_in[2];
    const float* Qw = (const float*)d_in[3];
    const float* Qb = (const float*)d_in[4];
    const float* Vw = (const float*)d_in[5];
    const float* Vb = (const float*)d_in[6];
    const float* Zw = (const float*)d_in[7];
    const float* Zb = (const float*)d_in[8];
    float* out = (float*)d_out;

    float* ws = (float*)d_ws;
    unsigned* Xksf16 = (unsigned*)(ws + XKS_OFF);
    unsigned* Q4     = (unsigned*)(ws + Q4_OFF);
    unsigned* Vt     = (unsigned*)(ws + VT_OFF);
    float* kn2       = ws + KN2_OFF;
    float* bmax      = ws + BMAX_OFF;
    float* part      = ws + PART_OFF;

    int nch = 32;
    const size_t avail = ws_size / 4;
    while (nch > 1 && (size_t)PART_OFF + (size_t)nch * 8192 * 9 > avail) nch >>= 1;
    const int ntiles = 256 / nch;   // 32-j tiles per wave (8192 j / (nch*32))

    proj_kernel<<<256, 256, 0, stream>>>(x, Kw, Kb, Qw, Qb, Vw, Vb,
                                         Xksf16, Q4, Vt, kn2, bmax);
    attn_kernel<<<64 * nch, 256, 0, stream>>>((const uint4*)Xksf16,
                                              (const uint4*)Q4, Vt, kn2,
                                              bmax, part, ntiles);
    finish_kernel<<<256, 256, 0, stream>>>(x, Zw, Zb, part, out, nch);
}